// Round 1
// baseline (2772.265 us; speedup 1.0000x reference)
//
#include <hip/hip_runtime.h>
#include <math.h>

#define D_MODEL 1024
#define N_HEADSC 16
#define DKH 64
#define D_FFC 4096

// ---------------- GEMM: C = act(A @ W + bias [+ res]) ----------------
// A: [M,K] row-major, W: [K,N] row-major, C: [M,N] row-major.
#define BM 128
#define BN 128
#define BKK 32

template<bool RELU, bool RES>
__launch_bounds__(256)
__global__ void gemm_bias_k(const float* __restrict__ A, const float* __restrict__ W,
                            const float* __restrict__ bias, const float* __restrict__ res,
                            float* __restrict__ C, int M, int N, int K) {
    __shared__ float As[BKK][BM + 4];
    __shared__ float Ws[BKK][BN + 4];
    const int tid = threadIdx.x;
    const int tx = tid & 15, ty = tid >> 4;
    const int brow = blockIdx.y * BM;
    const int bcol = blockIdx.x * BN;

    float acc[8][8];
    #pragma unroll
    for (int i = 0; i < 8; ++i)
        #pragma unroll
        for (int j = 0; j < 8; ++j) acc[i][j] = 0.f;

    for (int kb = 0; kb < K; kb += BKK) {
        // A tile 128x32 -> As transposed [k][m]
        #pragma unroll
        for (int c = 0; c < 4; ++c) {
            int idx = c * 256 + tid;            // 0..1023
            int row = idx >> 3;                 // 0..127
            int cg  = (idx & 7) << 2;           // 0,4,...,28
            float4 av = *(const float4*)&A[(size_t)(brow + row) * K + kb + cg];
            As[cg + 0][row] = av.x;
            As[cg + 1][row] = av.y;
            As[cg + 2][row] = av.z;
            As[cg + 3][row] = av.w;
        }
        // W tile 32x128 -> Ws natural [k][n]
        #pragma unroll
        for (int c = 0; c < 4; ++c) {
            int idx = c * 256 + tid;
            int kk = idx >> 5;                  // 0..31
            int cg = (idx & 31) << 2;           // 0..124
            *(float4*)&Ws[kk][cg] = *(const float4*)&W[(size_t)(kb + kk) * N + bcol + cg];
        }
        __syncthreads();

        #pragma unroll 8
        for (int kk = 0; kk < BKK; ++kk) {
            float a[8], b[8];
            *(float4*)&a[0] = *(const float4*)&As[kk][ty * 8];
            *(float4*)&a[4] = *(const float4*)&As[kk][ty * 8 + 4];
            *(float4*)&b[0] = *(const float4*)&Ws[kk][tx * 8];
            *(float4*)&b[4] = *(const float4*)&Ws[kk][tx * 8 + 4];
            #pragma unroll
            for (int i = 0; i < 8; ++i)
                #pragma unroll
                for (int j = 0; j < 8; ++j)
                    acc[i][j] += a[i] * b[j];
        }
        __syncthreads();
    }

    const int r0 = brow + ty * 8, c0 = bcol + tx * 8;
    #pragma unroll
    for (int i = 0; i < 8; ++i) {
        const size_t off = (size_t)(r0 + i) * N + c0;
        #pragma unroll
        for (int jj = 0; jj < 2; ++jj) {
            float4 b4 = *(const float4*)&bias[c0 + jj * 4];
            float4 ov;
            ov.x = acc[i][jj * 4 + 0] + b4.x;
            ov.y = acc[i][jj * 4 + 1] + b4.y;
            ov.z = acc[i][jj * 4 + 2] + b4.z;
            ov.w = acc[i][jj * 4 + 3] + b4.w;
            if (RES) {
                float4 rv = *(const float4*)&res[off + jj * 4];
                ov.x += rv.x; ov.y += rv.y; ov.z += rv.z; ov.w += rv.w;
            }
            if (RELU) {
                ov.x = fmaxf(ov.x, 0.f); ov.y = fmaxf(ov.y, 0.f);
                ov.z = fmaxf(ov.z, 0.f); ov.w = fmaxf(ov.w, 0.f);
            }
            *(float4*)&C[off + jj * 4] = ov;
        }
    }
}

// ---------------- Flash attention (causal), fp32 ----------------
// Q,K,V,O in [B,T,D] layout with head h occupying cols h*64..h*64+63.
// One block: one (b,h,q-tile of 64). 256 threads = 16x16, 4x4 per thread.
__launch_bounds__(256)
__global__ void attn_k(const float* __restrict__ Q, const float* __restrict__ Kp,
                       const float* __restrict__ V, float* __restrict__ O, int T) {
    const int D = D_MODEL;
    __shared__ float Qs[DKH][64 + 4];
    __shared__ float Ks[DKH][64 + 4];
    __shared__ float Vs[64][DKH + 4];
    __shared__ float Ps[64][64 + 4];
    __shared__ float m_s[64], l_s[64];
    const int tid = threadIdx.x;
    const int tx = tid & 15, ty = tid >> 4;
    const int qt = blockIdx.x, h = blockIdx.y, b = blockIdx.z;
    const size_t base = ((size_t)b * T) * D + h * DKH;

    // Q tile -> Qs transposed [d][q]
    #pragma unroll
    for (int c = 0; c < 4; ++c) {
        int idx = c * 256 + tid;
        int row = idx >> 4;
        int dg = (idx & 15) << 2;
        float4 qv = *(const float4*)&Q[base + (size_t)(qt * 64 + row) * D + dg];
        Qs[dg + 0][row] = qv.x; Qs[dg + 1][row] = qv.y;
        Qs[dg + 2][row] = qv.z; Qs[dg + 3][row] = qv.w;
    }
    if (tid < 64) { m_s[tid] = -1e30f; l_s[tid] = 0.f; }
    float o[4][4];
    #pragma unroll
    for (int i = 0; i < 4; ++i)
        #pragma unroll
        for (int j = 0; j < 4; ++j) o[i][j] = 0.f;
    __syncthreads();

    for (int kt = 0; kt <= qt; ++kt) {
        // K tile -> Ks transposed [d][s]; V tile -> Vs natural [s][d]
        #pragma unroll
        for (int c = 0; c < 4; ++c) {
            int idx = c * 256 + tid;
            int row = idx >> 4;
            int dg = (idx & 15) << 2;
            size_t gpos = base + (size_t)(kt * 64 + row) * D + dg;
            float4 kv = *(const float4*)&Kp[gpos];
            Ks[dg + 0][row] = kv.x; Ks[dg + 1][row] = kv.y;
            Ks[dg + 2][row] = kv.z; Ks[dg + 3][row] = kv.w;
            *(float4*)&Vs[row][dg] = *(const float4*)&V[gpos];
        }
        __syncthreads();

        // scores 4x4: rows ty*4+i, cols tx*4+j
        float s[4][4];
        #pragma unroll
        for (int i = 0; i < 4; ++i)
            #pragma unroll
            for (int j = 0; j < 4; ++j) s[i][j] = 0.f;
        #pragma unroll 8
        for (int d = 0; d < DKH; ++d) {
            float qa[4], kb[4];
            *(float4*)qa = *(const float4*)&Qs[d][ty * 4];
            *(float4*)kb = *(const float4*)&Ks[d][tx * 4];
            #pragma unroll
            for (int i = 0; i < 4; ++i)
                #pragma unroll
                for (int j = 0; j < 4; ++j)
                    s[i][j] += qa[i] * kb[j];
        }
        #pragma unroll
        for (int i = 0; i < 4; ++i)
            #pragma unroll
            for (int j = 0; j < 4; ++j) s[i][j] *= 0.125f;

        if (kt == qt) {
            #pragma unroll
            for (int i = 0; i < 4; ++i)
                #pragma unroll
                for (int j = 0; j < 4; ++j)
                    if (tx * 4 + j > ty * 4 + i) s[i][j] = -1e30f;
        }

        float alpha[4], mnew[4], rsum[4];
        #pragma unroll
        for (int i = 0; i < 4; ++i) {
            float rm = fmaxf(fmaxf(s[i][0], s[i][1]), fmaxf(s[i][2], s[i][3]));
            #pragma unroll
            for (int off = 1; off < 16; off <<= 1) rm = fmaxf(rm, __shfl_xor(rm, off));
            float mo = m_s[ty * 4 + i];
            float mn = fmaxf(mo, rm);
            mnew[i] = mn;
            alpha[i] = __expf(mo - mn);
            float rs = 0.f;
            #pragma unroll
            for (int j = 0; j < 4; ++j) { float p = __expf(s[i][j] - mn); s[i][j] = p; rs += p; }
            #pragma unroll
            for (int off = 1; off < 16; off <<= 1) rs += __shfl_xor(rs, off);
            rsum[i] = rs;
        }
        #pragma unroll
        for (int i = 0; i < 4; ++i)
            #pragma unroll
            for (int j = 0; j < 4; ++j) o[i][j] *= alpha[i];
        if (tx == 0) {
            #pragma unroll
            for (int i = 0; i < 4; ++i) {
                int r = ty * 4 + i;
                m_s[r] = mnew[i];
                l_s[r] = l_s[r] * alpha[i] + rsum[i];
            }
        }
        // P transposed -> Ps[s][q]
        #pragma unroll
        for (int i = 0; i < 4; ++i)
            #pragma unroll
            for (int j = 0; j < 4; ++j)
                Ps[tx * 4 + j][ty * 4 + i] = s[i][j];
        __syncthreads();

        // O += P @ V : rows ty*4+i (q), cols tx*4+j (d)
        #pragma unroll 8
        for (int kk = 0; kk < 64; ++kk) {
            float pv[4], vv[4];
            *(float4*)pv = *(const float4*)&Ps[kk][ty * 4];
            *(float4*)vv = *(const float4*)&Vs[kk][tx * 4];
            #pragma unroll
            for (int i = 0; i < 4; ++i)
                #pragma unroll
                for (int j = 0; j < 4; ++j)
                    o[i][j] += pv[i] * vv[j];
        }
        __syncthreads();
    }

    #pragma unroll
    for (int i = 0; i < 4; ++i) {
        float linv = 1.f / l_s[ty * 4 + i];
        float4 ov;
        ov.x = o[i][0] * linv; ov.y = o[i][1] * linv;
        ov.z = o[i][2] * linv; ov.w = o[i][3] * linv;
        *(float4*)&O[base + (size_t)(qt * 64 + ty * 4 + i) * D + tx * 4] = ov;
    }
}

// ---------------- LayerNorm over D=1024, one block per row ----------------
__launch_bounds__(256)
__global__ void ln_k(const float* __restrict__ X, const float* __restrict__ g,
                     const float* __restrict__ b, float* __restrict__ Y) {
    const int row = blockIdx.x;
    const int tid = threadIdx.x;
    const size_t off = (size_t)row * D_MODEL + tid * 4;
    float4 v = *(const float4*)&X[off];
    float s = v.x + v.y + v.z + v.w;
    float s2 = v.x * v.x + v.y * v.y + v.z * v.z + v.w * v.w;
    #pragma unroll
    for (int o = 1; o < 64; o <<= 1) { s += __shfl_xor(s, o); s2 += __shfl_xor(s2, o); }
    __shared__ float red[8];
    const int wid = tid >> 6, lane = tid & 63;
    if (lane == 0) { red[wid] = s; red[4 + wid] = s2; }
    __syncthreads();
    s = red[0] + red[1] + red[2] + red[3];
    s2 = red[4] + red[5] + red[6] + red[7];
    const float mu = s * (1.f / D_MODEL);
    const float var = s2 * (1.f / D_MODEL) - mu * mu;
    const float rst = rsqrtf(var + 1e-5f);
    float4 gv = *(const float4*)&g[tid * 4];
    float4 bv = *(const float4*)&b[tid * 4];
    float4 ov;
    ov.x = (v.x - mu) * rst * gv.x + bv.x;
    ov.y = (v.y - mu) * rst * gv.y + bv.y;
    ov.z = (v.z - mu) * rst * gv.z + bv.z;
    ov.w = (v.w - mu) * rst * gv.w + bv.w;
    *(float4*)&Y[off] = ov;
}

extern "C" void kernel_launch(void* const* d_in, const int* in_sizes, int n_in,
                              void* d_out, int out_size, void* d_ws, size_t ws_size,
                              hipStream_t stream) {
    (void)in_sizes; (void)n_in; (void)out_size; (void)ws_size;
    const float* x    = (const float*)d_in[0];
    const float* wq   = (const float*)d_in[1];
    const float* bq   = (const float*)d_in[2];
    const float* wk   = (const float*)d_in[3];
    const float* bk   = (const float*)d_in[4];
    const float* wv   = (const float*)d_in[5];
    const float* bv   = (const float*)d_in[6];
    const float* wo   = (const float*)d_in[7];
    const float* bo   = (const float*)d_in[8];
    const float* ln1g = (const float*)d_in[9];
    const float* ln1b = (const float*)d_in[10];
    const float* w1   = (const float*)d_in[11];
    const float* b1   = (const float*)d_in[12];
    const float* w2   = (const float*)d_in[13];
    const float* b2   = (const float*)d_in[14];
    const float* ln2g = (const float*)d_in[15];
    const float* ln2b = (const float*)d_in[16];
    float* out = (float*)d_out;

    const int B = 2, T = 2048, D = D_MODEL, F = D_FFC;
    const int M = B * T;                      // 4096
    const size_t S1 = (size_t)M * D;          // 4,194,304 floats
    float* ws  = (float*)d_ws;
    float* q   = ws;
    float* k   = ws + S1;
    float* v   = ws + 2 * S1;
    float* ao  = ws + 3 * S1;
    float* h1  = ws;                          // reuses q (dead after attention)
    float* mid = ws + S1;                     // 4*S1 long, reuses k/v/ao
    float* t1  = out;                         // pre-LN1 scratch in d_out

    dim3 blk(256);
    dim3 gD(D / BN, M / BM);                  // (8, 32)
    dim3 gF(F / BN, M / BM);                  // (32, 32)

    // QKV projections
    gemm_bias_k<false, false><<<gD, blk, 0, stream>>>(x, wq, bq, nullptr, q, M, D, D);
    gemm_bias_k<false, false><<<gD, blk, 0, stream>>>(x, wk, bk, nullptr, k, M, D, D);
    gemm_bias_k<false, false><<<gD, blk, 0, stream>>>(x, wv, bv, nullptr, v, M, D, D);

    // causal attention
    dim3 gA(T / 64, N_HEADSC, B);             // (32, 16, 2)
    attn_k<<<gA, blk, 0, stream>>>(q, k, v, ao, T);

    // output projection + residual -> t1 (=d_out scratch)
    gemm_bias_k<false, true><<<gD, blk, 0, stream>>>(ao, wo, bo, x, t1, M, D, D);
    // LN1 -> h1
    ln_k<<<M, 256, 0, stream>>>(t1, ln1g, ln1b, h1);
    // FFN1 (ReLU) -> mid
    gemm_bias_k<true, false><<<gF, blk, 0, stream>>>(h1, w1, b1, nullptr, mid, M, F, D);
    // FFN2 + residual(h1) -> d_out
    gemm_bias_k<false, true><<<gD, blk, 0, stream>>>(mid, w2, b2, h1, out, M, D, F);
    // LN2 in-place on d_out
    ln_k<<<M, 256, 0, stream>>>(out, ln2g, ln2b, out);
}

// Round 4
// 1197.549 us; speedup vs baseline: 2.3149x; 2.3149x over previous
//
#include <hip/hip_runtime.h>
#include <math.h>

#define D_MODEL 1024
#define N_HEADSC 16
#define DKH 64
#define D_FFC 4096

typedef short bf16x8 __attribute__((ext_vector_type(8)));
typedef float f32x4 __attribute__((ext_vector_type(4)));

#define GLOAD_LDS16(g, l)                                                      \
    __builtin_amdgcn_global_load_lds(                                          \
        (const __attribute__((address_space(1))) void*)(g),                    \
        (__attribute__((address_space(3))) void*)(l), 16, 0, 0)

__device__ inline unsigned short f2bf(float f) {
    unsigned u = __float_as_uint(f);
    u += 0x7fff + ((u >> 16) & 1);
    return (unsigned short)(u >> 16);
}
__device__ inline float bf2f(unsigned short h) {
    return __uint_as_float(((unsigned)h) << 16);
}

// ---------------- split-bf16 MFMA GEMM ----------------
// A2:  [M][2K] bf16 (hi plane cols 0..K-1, lo plane cols K..2K-1)
// Bt2: [N][2K] bf16 (W^T, hi|lo planes)
// C = (Ahi,Whi)+(Ahi,Wlo)+(Alo,Whi) ~= fp32 A@W
// BM=128 fixed; BN_=128 or 64. 256 threads (4 waves, 2x2 wave grid).
template<int BN_, bool RELU, bool RES, bool SPLIT>
__launch_bounds__(256)
__global__ void gemm_sb(const unsigned short* __restrict__ A2,
                        const unsigned short* __restrict__ Bt2,
                        const float* __restrict__ bias,
                        const float* __restrict__ res,
                        void* __restrict__ Cout,
                        int K, int N) {
    constexpr int BM_ = 128;
    constexpr int WCOLS = BN_ / 2;   // cols per wave
    constexpr int NT = WCOLS / 16;   // 16-col frags per wave
    __shared__ unsigned short As[BM_ * 32];
    __shared__ unsigned short Bs[BN_ * 32];
    const int tid = threadIdx.x;
    const int l = tid & 63, w = tid >> 6;
    const int wrow = w >> 1, wcol = w & 1;
    const int brow = blockIdx.y * BM_;
    const int bcol = blockIdx.x * BN_;
    const size_t ldk = 2 * (size_t)K;

    f32x4 acc[4][NT];
    #pragma unroll
    for (int mt = 0; mt < 4; ++mt)
        #pragma unroll
        for (int nt = 0; nt < NT; ++nt) acc[mt][nt] = (f32x4){0.f, 0.f, 0.f, 0.f};

    const int r0 = tid >> 2;           // staging row within 64
    const int c0 = (tid & 3) * 8;      // staging k-chunk
    const int lr = l & 15, kg = (l >> 4) * 8;

    #pragma unroll 1
    for (int t = 0; t < 3; ++t) {
        const int aBase = (t == 2) ? K : 0;
        const int wBase = (t == 1) ? K : 0;
        #pragma unroll 1
        for (int kb = 0; kb < K; kb += 32) {
            GLOAD_LDS16(A2 + (size_t)(brow + r0) * ldk + aBase + kb + c0, &As[tid * 8]);
            GLOAD_LDS16(A2 + (size_t)(brow + 64 + r0) * ldk + aBase + kb + c0, &As[(256 + tid) * 8]);
            GLOAD_LDS16(Bt2 + (size_t)(bcol + r0) * ldk + wBase + kb + c0, &Bs[tid * 8]);
            if constexpr (BN_ == 128) {
                GLOAD_LDS16(Bt2 + (size_t)(bcol + 64 + r0) * ldk + wBase + kb + c0, &Bs[(256 + tid) * 8]);
            }
            __syncthreads();

            bf16x8 af[4], bfr[NT];
            #pragma unroll
            for (int mt = 0; mt < 4; ++mt)
                af[mt] = *(const bf16x8*)&As[(wrow * 64 + mt * 16 + lr) * 32 + kg];
            #pragma unroll
            for (int nt = 0; nt < NT; ++nt)
                bfr[nt] = *(const bf16x8*)&Bs[(wcol * WCOLS + nt * 16 + lr) * 32 + kg];
            #pragma unroll
            for (int mt = 0; mt < 4; ++mt)
                #pragma unroll
                for (int nt = 0; nt < NT; ++nt)
                    acc[mt][nt] = __builtin_amdgcn_mfma_f32_16x16x32_bf16(
                        af[mt], bfr[nt], acc[mt][nt], 0, 0, 0);
            __syncthreads();
        }
    }

    const int lg = l >> 4;
    #pragma unroll
    for (int mt = 0; mt < 4; ++mt) {
        #pragma unroll
        for (int nt = 0; nt < NT; ++nt) {
            #pragma unroll
            for (int j = 0; j < 4; ++j) {
                const int row = brow + wrow * 64 + mt * 16 + lg * 4 + j;
                const int col = bcol + wcol * WCOLS + nt * 16 + lr;
                float v = acc[mt][nt][j] + bias[col];
                if (RES) v += res[(size_t)row * N + col];
                if (RELU) v = fmaxf(v, 0.f);
                if (SPLIT) {
                    unsigned short hi = f2bf(v);
                    unsigned short lo = f2bf(v - bf2f(hi));
                    unsigned short* C = (unsigned short*)Cout;
                    C[(size_t)row * (2 * (size_t)N) + col] = hi;
                    C[(size_t)row * (2 * (size_t)N) + N + col] = lo;
                } else {
                    ((float*)Cout)[(size_t)row * N + col] = v;
                }
            }
        }
    }
}

// ---------------- weight transpose + split: W[K,N] f32 -> Wt2[N][ldo] bf16 ----------------
__launch_bounds__(256)
__global__ void wsplit_t_k(const float* __restrict__ W, unsigned short* __restrict__ Wt2,
                           int K, int N, int ldo) {
    __shared__ float T[32][33];
    const int tx = threadIdx.x & 31, ty = threadIdx.x >> 5;
    const int k0 = blockIdx.y * 32, n0 = blockIdx.x * 32;
    #pragma unroll
    for (int i = 0; i < 4; ++i)
        T[i * 8 + ty][tx] = W[(size_t)(k0 + i * 8 + ty) * N + n0 + tx];
    __syncthreads();
    #pragma unroll
    for (int i = 0; i < 4; ++i) {
        const int r = i * 8 + ty;
        const float v = T[tx][r];
        const unsigned short hi = f2bf(v);
        const unsigned short lo = f2bf(v - bf2f(hi));
        Wt2[(size_t)(n0 + r) * ldo + k0 + tx] = hi;
        Wt2[(size_t)(n0 + r) * ldo + K + k0 + tx] = lo;
    }
}

// ---------------- activation split: X[M,1024] f32 -> X2[M][2048] bf16 ----------------
__launch_bounds__(256)
__global__ void split2_k(const float* __restrict__ X, unsigned short* __restrict__ X2) {
    const int idx = (blockIdx.x * 256 + threadIdx.x) * 4;
    const int r = idx >> 10, c = idx & 1023;
    float4 v = *(const float4*)&X[idx];
    ushort4 h, lo;
    h.x = f2bf(v.x); lo.x = f2bf(v.x - bf2f(h.x));
    h.y = f2bf(v.y); lo.y = f2bf(v.y - bf2f(h.y));
    h.z = f2bf(v.z); lo.z = f2bf(v.z - bf2f(h.z));
    h.w = f2bf(v.w); lo.w = f2bf(v.w - bf2f(h.w));
    *(ushort4*)&X2[(size_t)r * 2048 + c] = h;
    *(ushort4*)&X2[(size_t)r * 2048 + 1024 + c] = lo;
}

__global__ void biascat_k(const float* a, const float* b, const float* c, float* o) {
    const int i = blockIdx.x * 256 + threadIdx.x;
    o[i] = (i < 1024) ? a[i] : ((i < 2048) ? b[i - 1024] : c[i - 2048]);
}

// ---------------- Flash attention (causal), fp32, strided qkv input ----------------
// QKV: [B*T][3072] f32 (q|k|v). Output: ao2 [B*T][2048] split-bf16.
__launch_bounds__(256)
__global__ void attn_k(const float* __restrict__ QKV, unsigned short* __restrict__ O2, int T) {
    const int LD = 3 * D_MODEL;
    __shared__ float Qs[DKH][64 + 4];
    __shared__ float Ks[DKH][64 + 4];
    __shared__ float Vs[64][DKH + 4];
    __shared__ float Ps[64][64 + 4];
    __shared__ float m_s[64], l_s[64];
    const int tid = threadIdx.x;
    const int tx = tid & 15, ty = tid >> 4;
    const int qt = blockIdx.x, h = blockIdx.y, b = blockIdx.z;
    const size_t base = ((size_t)b * T) * LD + h * DKH;

    #pragma unroll
    for (int c = 0; c < 4; ++c) {
        int idx = c * 256 + tid;
        int row = idx >> 4;
        int dg = (idx & 15) << 2;
        float4 qv = *(const float4*)&QKV[base + (size_t)(qt * 64 + row) * LD + dg];
        Qs[dg + 0][row] = qv.x; Qs[dg + 1][row] = qv.y;
        Qs[dg + 2][row] = qv.z; Qs[dg + 3][row] = qv.w;
    }
    if (tid < 64) { m_s[tid] = -1e30f; l_s[tid] = 0.f; }
    float o[4][4];
    #pragma unroll
    for (int i = 0; i < 4; ++i)
        #pragma unroll
        for (int j = 0; j < 4; ++j) o[i][j] = 0.f;
    __syncthreads();

    for (int kt = 0; kt <= qt; ++kt) {
        #pragma unroll
        for (int c = 0; c < 4; ++c) {
            int idx = c * 256 + tid;
            int row = idx >> 4;
            int dg = (idx & 15) << 2;
            size_t gpos = base + (size_t)(kt * 64 + row) * LD + dg;
            float4 kv = *(const float4*)&QKV[gpos + D_MODEL];
            Ks[dg + 0][row] = kv.x; Ks[dg + 1][row] = kv.y;
            Ks[dg + 2][row] = kv.z; Ks[dg + 3][row] = kv.w;
            *(float4*)&Vs[row][dg] = *(const float4*)&QKV[gpos + 2 * D_MODEL];
        }
        __syncthreads();

        float s[4][4];
        #pragma unroll
        for (int i = 0; i < 4; ++i)
            #pragma unroll
            for (int j = 0; j < 4; ++j) s[i][j] = 0.f;
        #pragma unroll 8
        for (int d = 0; d < DKH; ++d) {
            float qa[4], kb[4];
            *(float4*)qa = *(const float4*)&Qs[d][ty * 4];
            *(float4*)kb = *(const float4*)&Ks[d][tx * 4];
            #pragma unroll
            for (int i = 0; i < 4; ++i)
                #pragma unroll
                for (int j = 0; j < 4; ++j)
                    s[i][j] += qa[i] * kb[j];
        }
        #pragma unroll
        for (int i = 0; i < 4; ++i)
            #pragma unroll
            for (int j = 0; j < 4; ++j) s[i][j] *= 0.125f;

        if (kt == qt) {
            #pragma unroll
            for (int i = 0; i < 4; ++i)
                #pragma unroll
                for (int j = 0; j < 4; ++j)
                    if (tx * 4 + j > ty * 4 + i) s[i][j] = -1e30f;
        }

        float alpha[4], mnew[4], rsum[4];
        #pragma unroll
        for (int i = 0; i < 4; ++i) {
            float rm = fmaxf(fmaxf(s[i][0], s[i][1]), fmaxf(s[i][2], s[i][3]));
            #pragma unroll
            for (int off = 1; off < 16; off <<= 1) rm = fmaxf(rm, __shfl_xor(rm, off));
            float mo = m_s[ty * 4 + i];
            float mn = fmaxf(mo, rm);
            mnew[i] = mn;
            alpha[i] = __expf(mo - mn);
            float rs = 0.f;
            #pragma unroll
            for (int j = 0; j < 4; ++j) { float p = __expf(s[i][j] - mn); s[i][j] = p; rs += p; }
            #pragma unroll
            for (int off = 1; off < 16; off <<= 1) rs += __shfl_xor(rs, off);
            rsum[i] = rs;
        }
        #pragma unroll
        for (int i = 0; i < 4; ++i)
            #pragma unroll
            for (int j = 0; j < 4; ++j) o[i][j] *= alpha[i];
        if (tx == 0) {
            #pragma unroll
            for (int i = 0; i < 4; ++i) {
                int r = ty * 4 + i;
                m_s[r] = mnew[i];
                l_s[r] = l_s[r] * alpha[i] + rsum[i];
            }
        }
        #pragma unroll
        for (int i = 0; i < 4; ++i)
            #pragma unroll
            for (int j = 0; j < 4; ++j)
                Ps[tx * 4 + j][ty * 4 + i] = s[i][j];
        __syncthreads();

        #pragma unroll 8
        for (int kk = 0; kk < 64; ++kk) {
            float pv[4], vv[4];
            *(float4*)pv = *(const float4*)&Ps[kk][ty * 4];
            *(float4*)vv = *(const float4*)&Vs[kk][tx * 4];
            #pragma unroll
            for (int i = 0; i < 4; ++i)
                #pragma unroll
                for (int j = 0; j < 4; ++j)
                    o[i][j] += pv[i] * vv[j];
        }
        __syncthreads();
    }

    #pragma unroll
    for (int i = 0; i < 4; ++i) {
        const float linv = 1.f / l_s[ty * 4 + i];
        const size_t m = (size_t)b * T + qt * 64 + ty * 4 + i;
        ushort4 h4, lo4;
        float v0 = o[i][0] * linv, v1 = o[i][1] * linv, v2 = o[i][2] * linv, v3 = o[i][3] * linv;
        h4.x = f2bf(v0); lo4.x = f2bf(v0 - bf2f(h4.x));
        h4.y = f2bf(v1); lo4.y = f2bf(v1 - bf2f(h4.y));
        h4.z = f2bf(v2); lo4.z = f2bf(v2 - bf2f(h4.z));
        h4.w = f2bf(v3); lo4.w = f2bf(v3 - bf2f(h4.w));
        *(ushort4*)&O2[m * 2048 + h * DKH + tx * 4] = h4;
        *(ushort4*)&O2[m * 2048 + 1024 + h * DKH + tx * 4] = lo4;
    }
}

// ---------------- LayerNorm over D=1024; optional split-bf16 side output ----------------
// Safe to call with Y == X (in-place): each thread reads exactly the
// elements it later writes.
template<bool SPLIT>
__launch_bounds__(256)
__global__ void ln_k(const float* __restrict__ X, const float* __restrict__ g,
                     const float* __restrict__ b, float* __restrict__ Y,
                     unsigned short* __restrict__ Y2) {
    const int row = blockIdx.x;
    const int tid = threadIdx.x;
    const size_t off = (size_t)row * D_MODEL + tid * 4;
    float4 v = *(const float4*)&X[off];
    float s = v.x + v.y + v.z + v.w;
    float s2 = v.x * v.x + v.y * v.y + v.z * v.z + v.w * v.w;
    #pragma unroll
    for (int o = 1; o < 64; o <<= 1) { s += __shfl_xor(s, o); s2 += __shfl_xor(s2, o); }
    __shared__ float red[8];
    const int wid = tid >> 6, lane = tid & 63;
    if (lane == 0) { red[wid] = s; red[4 + wid] = s2; }
    __syncthreads();
    s = red[0] + red[1] + red[2] + red[3];
    s2 = red[4] + red[5] + red[6] + red[7];
    const float mu = s * (1.f / D_MODEL);
    const float var = s2 * (1.f / D_MODEL) - mu * mu;
    const float rst = rsqrtf(var + 1e-5f);
    float4 gv = *(const float4*)&g[tid * 4];
    float4 bv = *(const float4*)&b[tid * 4];
    float4 ov;
    ov.x = (v.x - mu) * rst * gv.x + bv.x;
    ov.y = (v.y - mu) * rst * gv.y + bv.y;
    ov.z = (v.z - mu) * rst * gv.z + bv.z;
    ov.w = (v.w - mu) * rst * gv.w + bv.w;
    *(float4*)&Y[off] = ov;
    if (SPLIT) {
        ushort4 h4, lo4;
        h4.x = f2bf(ov.x); lo4.x = f2bf(ov.x - bf2f(h4.x));
        h4.y = f2bf(ov.y); lo4.y = f2bf(ov.y - bf2f(h4.y));
        h4.z = f2bf(ov.z); lo4.z = f2bf(ov.z - bf2f(h4.z));
        h4.w = f2bf(ov.w); lo4.w = f2bf(ov.w - bf2f(h4.w));
        *(ushort4*)&Y2[(size_t)row * 2048 + tid * 4] = h4;
        *(ushort4*)&Y2[(size_t)row * 2048 + 1024 + tid * 4] = lo4;
    }
}

extern "C" void kernel_launch(void* const* d_in, const int* in_sizes, int n_in,
                              void* d_out, int out_size, void* d_ws, size_t ws_size,
                              hipStream_t stream) {
    (void)in_sizes; (void)n_in; (void)out_size; (void)ws_size;
    const float* x    = (const float*)d_in[0];
    const float* wq   = (const float*)d_in[1];
    const float* bq   = (const float*)d_in[2];
    const float* wk   = (const float*)d_in[3];
    const float* bk   = (const float*)d_in[4];
    const float* wv   = (const float*)d_in[5];
    const float* bv   = (const float*)d_in[6];
    const float* wo   = (const float*)d_in[7];
    const float* bo   = (const float*)d_in[8];
    const float* ln1g = (const float*)d_in[9];
    const float* ln1b = (const float*)d_in[10];
    const float* w1   = (const float*)d_in[11];
    const float* b1   = (const float*)d_in[12];
    const float* w2   = (const float*)d_in[13];
    const float* b2   = (const float*)d_in[14];
    const float* ln2g = (const float*)d_in[15];
    const float* ln2b = (const float*)d_in[16];
    float* out = (float*)d_out;

    const int B = 2, T = 2048, D = D_MODEL, F = D_FFC;
    const int M = B * T;                       // 4096

    // ws layout (byte offsets), peak 112 MB + 12 KB.
    // Aliasing timeline (stream-ordered, each region dead before its reuse):
    //   [0,48)    qkv f32        (live: step3 -> step5)   then mid2 [0,64) at step9
    //   [48,64)   x2             (live: step2 -> step3)
    //   [64,76)   wqkv2t         (live: step1 -> step3)   then w1t  [64,80) at step4
    //   [80,96)   ao2            (live: step5 -> step6)   then h12  [80,96) at step8
    //   [96,100)  wo2t           (live: step1 -> step6)   then w2t  [96,112) at step7
    //   [112,+12K) bqkv
    char* ws = (char*)d_ws;
    const size_t MB = 1048576;
    float*          qkv    = (float*)(ws + 0);                 // [M][3072] f32
    unsigned short* mid2   = (unsigned short*)(ws + 0);        // [M][8192] bf16
    unsigned short* x2     = (unsigned short*)(ws + 48 * MB);  // [M][2048] bf16
    unsigned short* wslotA = (unsigned short*)(ws + 64 * MB);  // wqkv2t -> w1t
    unsigned short* ao2    = (unsigned short*)(ws + 80 * MB);  // [M][2048] bf16
    unsigned short* h12    = (unsigned short*)(ws + 80 * MB);  // [M][2048] bf16 (reuses ao2)
    unsigned short* wslotB = (unsigned short*)(ws + 96 * MB);  // wo2t -> w22t
    float*          bqkv   = (float*)(ws + 112 * MB);          // 12KB

    dim3 blk(256);

    // 1. weight transpose+split for QKV (into fused [3072][2048]) and Wo
    wsplit_t_k<<<dim3(32, 32), blk, 0, stream>>>(wq, wslotA + 0    * (size_t)2048, D, D, 2048);
    wsplit_t_k<<<dim3(32, 32), blk, 0, stream>>>(wk, wslotA + 1024 * (size_t)2048, D, D, 2048);
    wsplit_t_k<<<dim3(32, 32), blk, 0, stream>>>(wv, wslotA + 2048 * (size_t)2048, D, D, 2048);
    wsplit_t_k<<<dim3(32, 32), blk, 0, stream>>>(wo, wslotB, D, D, 2048);
    // 2. x -> split bf16; bias concat
    split2_k<<<4096, blk, 0, stream>>>(x, x2);
    biascat_k<<<12, blk, 0, stream>>>(bq, bk, bv, bqkv);

    // 3. fused QKV projection: [M][2048]x[3072][2048] -> qkv f32 [M][3072]
    gemm_sb<128, false, false, false><<<dim3(24, 32), blk, 0, stream>>>(
        x2, wslotA, bqkv, nullptr, qkv, D, 3 * D);

    // 4. w1 transpose+split (overwrites wqkv slot — stream-ordered, safe)
    wsplit_t_k<<<dim3(128, 32), blk, 0, stream>>>(w1, wslotA, D, F, 2048);

    // 5. causal attention -> ao2 split-bf16
    attn_k<<<dim3(T / 64, N_HEADSC, B), blk, 0, stream>>>(qkv, ao2, T);

    // 6. output projection + residual(x) -> d_out (pre-LN1, f32)
    gemm_sb<64, false, true, false><<<dim3(16, 32), blk, 0, stream>>>(
        ao2, wslotB, bo, x, out, D, D);

    // 7. w2 transpose+split (overwrites wo slot)
    wsplit_t_k<<<dim3(32, 128), blk, 0, stream>>>(w2, wslotB, F, D, 8192);

    // 8. LN1 in-place on d_out (h stays in d_out as FFN2's residual) + h12 split
    ln_k<true><<<M, blk, 0, stream>>>(out, ln1g, ln1b, out, h12);

    // 9. FFN1 + ReLU -> mid2 split-bf16 [M][8192]
    gemm_sb<128, true, false, true><<<dim3(32, 32), blk, 0, stream>>>(
        h12, wslotA, b1, nullptr, mid2, D, F);

    // 10. FFN2 + residual(d_out = h) -> d_out in-place (same-index read/write)
    gemm_sb<64, false, true, false><<<dim3(16, 32), blk, 0, stream>>>(
        mid2, wslotB, b2, out, out, F, D);

    // 11. LN2 in-place
    ln_k<false><<<M, blk, 0, stream>>>(out, ln2g, ln2b, out, nullptr);
}

// Round 5
// 790.422 us; speedup vs baseline: 3.5073x; 1.5151x over previous
//
#include <hip/hip_runtime.h>
#include <math.h>

#define D_MODEL 1024
#define N_HEADSC 16
#define DKH 64
#define D_FFC 4096

typedef short bf16x8 __attribute__((ext_vector_type(8)));
typedef float f32x4 __attribute__((ext_vector_type(4)));

#define GLOAD_LDS16(g, l)                                                      \
    __builtin_amdgcn_global_load_lds(                                          \
        (const __attribute__((address_space(1))) void*)(g),                    \
        (__attribute__((address_space(3))) void*)(l), 16, 0, 0)

__device__ inline unsigned short f2bf(float f) {
    unsigned u = __float_as_uint(f);
    u += 0x7fff + ((u >> 16) & 1);
    return (unsigned short)(u >> 16);
}
__device__ inline float bf2f(unsigned short h) {
    return __uint_as_float(((unsigned)h) << 16);
}

// ---------------- split-bf16 MFMA GEMM (verified round-4 structure) ----------------
// A2: [M][2K] bf16 (hi|lo planes), Bt2: [N][2K] bf16 (W^T, hi|lo).
// C = Ahi*Whi + Ahi*Wlo + Alo*Whi ~= fp32 A@W.
template<int BN_, bool RELU, bool RES, bool SPLIT>
__launch_bounds__(256)
__global__ void gemm_sb(const unsigned short* __restrict__ A2,
                        const unsigned short* __restrict__ Bt2,
                        const float* __restrict__ bias,
                        const float* __restrict__ res,
                        void* __restrict__ Cout,
                        int K, int N) {
    constexpr int BM_ = 128;
    constexpr int WCOLS = BN_ / 2;
    constexpr int NT = WCOLS / 16;
    __shared__ unsigned short As[BM_ * 32];
    __shared__ unsigned short Bs[BN_ * 32];
    const int tid = threadIdx.x;
    const int l = tid & 63, w = tid >> 6;
    const int wrow = w >> 1, wcol = w & 1;
    const int brow = blockIdx.y * BM_;
    const int bcol = blockIdx.x * BN_;
    const size_t ldk = 2 * (size_t)K;

    f32x4 acc[4][NT];
    #pragma unroll
    for (int mt = 0; mt < 4; ++mt)
        #pragma unroll
        for (int nt = 0; nt < NT; ++nt) acc[mt][nt] = (f32x4){0.f, 0.f, 0.f, 0.f};

    const int r0 = tid >> 2;
    const int c0 = (tid & 3) * 8;
    const int lr = l & 15, kg = (l >> 4) * 8;

    #pragma unroll 1
    for (int t = 0; t < 3; ++t) {
        const int aBase = (t == 2) ? K : 0;
        const int wBase = (t == 1) ? K : 0;
        #pragma unroll 1
        for (int kb = 0; kb < K; kb += 32) {
            GLOAD_LDS16(A2 + (size_t)(brow + r0) * ldk + aBase + kb + c0, &As[tid * 8]);
            GLOAD_LDS16(A2 + (size_t)(brow + 64 + r0) * ldk + aBase + kb + c0, &As[(256 + tid) * 8]);
            GLOAD_LDS16(Bt2 + (size_t)(bcol + r0) * ldk + wBase + kb + c0, &Bs[tid * 8]);
            if constexpr (BN_ == 128) {
                GLOAD_LDS16(Bt2 + (size_t)(bcol + 64 + r0) * ldk + wBase + kb + c0, &Bs[(256 + tid) * 8]);
            }
            __syncthreads();

            bf16x8 af[4], bfr[NT];
            #pragma unroll
            for (int mt = 0; mt < 4; ++mt)
                af[mt] = *(const bf16x8*)&As[(wrow * 64 + mt * 16 + lr) * 32 + kg];
            #pragma unroll
            for (int nt = 0; nt < NT; ++nt)
                bfr[nt] = *(const bf16x8*)&Bs[(wcol * WCOLS + nt * 16 + lr) * 32 + kg];
            #pragma unroll
            for (int mt = 0; mt < 4; ++mt)
                #pragma unroll
                for (int nt = 0; nt < NT; ++nt)
                    acc[mt][nt] = __builtin_amdgcn_mfma_f32_16x16x32_bf16(
                        af[mt], bfr[nt], acc[mt][nt], 0, 0, 0);
            __syncthreads();
        }
    }

    const int lg = l >> 4;
    #pragma unroll
    for (int mt = 0; mt < 4; ++mt) {
        #pragma unroll
        for (int nt = 0; nt < NT; ++nt) {
            #pragma unroll
            for (int j = 0; j < 4; ++j) {
                const int row = brow + wrow * 64 + mt * 16 + lg * 4 + j;
                const int col = bcol + wcol * WCOLS + nt * 16 + lr;
                float v = acc[mt][nt][j] + bias[col];
                if (RES) v += res[(size_t)row * N + col];
                if (RELU) v = fmaxf(v, 0.f);
                if (SPLIT) {
                    unsigned short hi = f2bf(v);
                    unsigned short lo = f2bf(v - bf2f(hi));
                    unsigned short* C = (unsigned short*)Cout;
                    C[(size_t)row * (2 * (size_t)N) + col] = hi;
                    C[(size_t)row * (2 * (size_t)N) + N + col] = lo;
                } else {
                    ((float*)Cout)[(size_t)row * N + col] = v;
                }
            }
        }
    }
}

// ---------------- QKV GEMM: same core, attention-ready epilogue ----------------
// Q cols scaled by 1/8 (exact), Q|K -> qk2 [M][4096] split; V -> vT2 [bh][pl][d][T] split.
__launch_bounds__(256)
__global__ void gemm_qkv(const unsigned short* __restrict__ A2,
                         const unsigned short* __restrict__ Bt2,
                         const float* __restrict__ bias,
                         unsigned short* __restrict__ qk2,
                         unsigned short* __restrict__ vT2,
                         int K, int N) {
    __shared__ unsigned short As[128 * 32];
    __shared__ unsigned short Bs[128 * 32];
    const int tid = threadIdx.x;
    const int l = tid & 63, w = tid >> 6;
    const int wrow = w >> 1, wcol = w & 1;
    const int brow = blockIdx.y * 128;
    const int bcol = blockIdx.x * 128;
    const size_t ldk = 2 * (size_t)K;

    f32x4 acc[4][4];
    #pragma unroll
    for (int mt = 0; mt < 4; ++mt)
        #pragma unroll
        for (int nt = 0; nt < 4; ++nt) acc[mt][nt] = (f32x4){0.f, 0.f, 0.f, 0.f};

    const int r0 = tid >> 2;
    const int c0 = (tid & 3) * 8;
    const int lr = l & 15, kg = (l >> 4) * 8;

    #pragma unroll 1
    for (int t = 0; t < 3; ++t) {
        const int aBase = (t == 2) ? K : 0;
        const int wBase = (t == 1) ? K : 0;
        #pragma unroll 1
        for (int kb = 0; kb < K; kb += 32) {
            GLOAD_LDS16(A2 + (size_t)(brow + r0) * ldk + aBase + kb + c0, &As[tid * 8]);
            GLOAD_LDS16(A2 + (size_t)(brow + 64 + r0) * ldk + aBase + kb + c0, &As[(256 + tid) * 8]);
            GLOAD_LDS16(Bt2 + (size_t)(bcol + r0) * ldk + wBase + kb + c0, &Bs[tid * 8]);
            GLOAD_LDS16(Bt2 + (size_t)(bcol + 64 + r0) * ldk + wBase + kb + c0, &Bs[(256 + tid) * 8]);
            __syncthreads();

            bf16x8 af[4], bfr[4];
            #pragma unroll
            for (int mt = 0; mt < 4; ++mt)
                af[mt] = *(const bf16x8*)&As[(wrow * 64 + mt * 16 + lr) * 32 + kg];
            #pragma unroll
            for (int nt = 0; nt < 4; ++nt)
                bfr[nt] = *(const bf16x8*)&Bs[(wcol * 64 + nt * 16 + lr) * 32 + kg];
            #pragma unroll
            for (int mt = 0; mt < 4; ++mt)
                #pragma unroll
                for (int nt = 0; nt < 4; ++nt)
                    acc[mt][nt] = __builtin_amdgcn_mfma_f32_16x16x32_bf16(
                        af[mt], bfr[nt], acc[mt][nt], 0, 0, 0);
            __syncthreads();
        }
    }

    const int lg = l >> 4;
    #pragma unroll
    for (int mt = 0; mt < 4; ++mt) {
        #pragma unroll
        for (int nt = 0; nt < 4; ++nt) {
            #pragma unroll
            for (int j = 0; j < 4; ++j) {
                const int row = brow + wrow * 64 + mt * 16 + lg * 4 + j;
                const int col = bcol + wcol * 64 + nt * 16 + lr;
                float v = acc[mt][nt][j] + bias[col];
                if (col < 1024) v *= 0.125f;   // fold 1/sqrt(dk) into Q (exact)
                const unsigned short hi = f2bf(v);
                const unsigned short lo = f2bf(v - bf2f(hi));
                if (col < 2048) {
                    qk2[(size_t)row * 4096 + col] = hi;
                    qk2[(size_t)row * 4096 + 2048 + col] = lo;
                } else {
                    const int vc = col - 2048, hh = vc >> 6, dd = vc & 63;
                    const int bb = row >> 11, tt = row & 2047;
                    const size_t basev = ((size_t)((bb * 16 + hh) * 2) * 64 + dd) * 2048 + tt;
                    vT2[basev] = hi;
                    vT2[basev + (size_t)64 * 2048] = lo;
                }
            }
        }
    }
}

// ---------------- MFMA flash attention (causal), split-bf16 precision ----------------
// qk2: [M][4096] (Q|K hi at 0..2047, lo at 2048..4095), Q pre-scaled by 1/8.
// vT2: [bh][plane][d=64][T] bf16. Output ao2: [M][2048] split-bf16.
// Block: 128 q-rows, 4 waves (32 q each). KV tiles of 64.
__launch_bounds__(256)
__global__ void attn_mfma(const unsigned short* __restrict__ qk2,
                          const unsigned short* __restrict__ vT2,
                          unsigned short* __restrict__ ao2) {
    constexpr int T = 2048;
    // [64 rows][8 chunks of 8 bf16], stored chunk = logical ^ (row&7)
    __shared__ unsigned short KsHi[4096], KsLo[4096], VsHi[4096], VsLo[4096];

    const int tid = threadIdx.x;
    const int l = tid & 63, w = tid >> 6;
    const int g = l >> 4, q15 = l & 15;
    const int bh = blockIdx.x, b = bh >> 4, h = bh & 15;
    const int qbr = blockIdx.y;
    const int qb = (qbr < 8) ? qbr : 23 - qbr;   // pair qb + (15-qb) per CU
    const int qw = qb * 128 + w * 32;            // wave q base

    // Q B-frags (registers, reused across all KV tiles)
    bf16x8 qhi[2][2], qlo[2][2];
    #pragma unroll
    for (int qf = 0; qf < 2; ++qf)
        #pragma unroll
        for (int kc = 0; kc < 2; ++kc) {
            const size_t m = (size_t)b * T + qw + qf * 16 + q15;
            qhi[qf][kc] = *(const bf16x8*)&qk2[m * 4096 + h * 64 + kc * 32 + g * 8];
            qlo[qf][kc] = *(const bf16x8*)&qk2[m * 4096 + 2048 + h * 64 + kc * 32 + g * 8];
        }

    f32x4 out[2][4];
    #pragma unroll
    for (int qf = 0; qf < 2; ++qf)
        #pragma unroll
        for (int df = 0; df < 4; ++df) out[qf][df] = (f32x4){0.f, 0.f, 0.f, 0.f};
    float mreg[2] = {-1e30f, -1e30f};
    float lreg[2] = {0.f, 0.f};

    const int ntiles = 2 * qb + 2;
    const size_t kvVbase0 = ((size_t)(bh * 2 + 0) * 64) * 2048;
    const size_t kvVbase1 = ((size_t)(bh * 2 + 1) * 64) * 2048;

    for (int kt = 0; kt < ntiles; ++kt) {
        const int kv0 = kt * 64;
        // ---- stage K,V tiles (swizzled source, linear LDS dest) ----
        #pragma unroll
        for (int rr = 0; rr < 2; ++rr) {
            const int slot = rr * 256 + tid;
            const int row = slot >> 3, c = slot & 7;
            const int cs = (c ^ (row & 7)) * 8;
            const size_t krow = (size_t)(b * T + kv0 + row) * 4096;
            GLOAD_LDS16(qk2 + krow + 1024 + h * 64 + cs, &KsHi[slot * 8]);
            GLOAD_LDS16(qk2 + krow + 3072 + h * 64 + cs, &KsLo[slot * 8]);
            GLOAD_LDS16(vT2 + kvVbase0 + (size_t)row * 2048 + kv0 + cs, &VsHi[slot * 8]);
            GLOAD_LDS16(vT2 + kvVbase1 + (size_t)row * 2048 + kv0 + cs, &VsLo[slot * 8]);
        }
        __syncthreads();

        if (kv0 <= qw + 31) {   // wave-uniform: skip fully-masked tiles
            // ---- S^T = K . Q^T (3-term split) ----
            f32x4 sT[4][2];
            #pragma unroll
            for (int kvf = 0; kvf < 4; ++kvf)
                #pragma unroll
                for (int qf = 0; qf < 2; ++qf) sT[kvf][qf] = (f32x4){0.f, 0.f, 0.f, 0.f};
            #pragma unroll
            for (int kvf = 0; kvf < 4; ++kvf) {
                const int rowk = kvf * 16 + q15, sw = rowk & 7;
                bf16x8 khi[2], klo[2];
                #pragma unroll
                for (int kc = 0; kc < 2; ++kc) {
                    khi[kc] = *(const bf16x8*)&KsHi[rowk * 64 + ((kc * 4 + g) ^ sw) * 8];
                    klo[kc] = *(const bf16x8*)&KsLo[rowk * 64 + ((kc * 4 + g) ^ sw) * 8];
                }
                #pragma unroll
                for (int qf = 0; qf < 2; ++qf)
                    #pragma unroll
                    for (int kc = 0; kc < 2; ++kc) {
                        sT[kvf][qf] = __builtin_amdgcn_mfma_f32_16x16x32_bf16(khi[kc], qhi[qf][kc], sT[kvf][qf], 0, 0, 0);
                        sT[kvf][qf] = __builtin_amdgcn_mfma_f32_16x16x32_bf16(khi[kc], qlo[qf][kc], sT[kvf][qf], 0, 0, 0);
                        sT[kvf][qf] = __builtin_amdgcn_mfma_f32_16x16x32_bf16(klo[kc], qhi[qf][kc], sT[kvf][qf], 0, 0, 0);
                    }
            }
            // ---- causal mask (diagonal-straddling tiles only) ----
            if (kv0 + 63 > qw) {
                #pragma unroll
                for (int kvf = 0; kvf < 4; ++kvf)
                    #pragma unroll
                    for (int qf = 0; qf < 2; ++qf)
                        #pragma unroll
                        for (int j = 0; j < 4; ++j) {
                            const int kvg = kv0 + kvf * 16 + g * 4 + j;
                            const int qg = qw + qf * 16 + q15;
                            if (kvg > qg) sT[kvf][qf][j] = -1e30f;
                        }
            }
            // ---- online softmax stats (per q = column), rescale out ----
            float alphaq[2];
            #pragma unroll
            for (int qf = 0; qf < 2; ++qf) {
                float tmax = -1e30f;
                #pragma unroll
                for (int kvf = 0; kvf < 4; ++kvf)
                    #pragma unroll
                    for (int j = 0; j < 4; ++j) tmax = fmaxf(tmax, sT[kvf][qf][j]);
                tmax = fmaxf(tmax, __shfl_xor(tmax, 16));
                tmax = fmaxf(tmax, __shfl_xor(tmax, 32));
                const float mn = fmaxf(mreg[qf], tmax);
                alphaq[qf] = __expf(mreg[qf] - mn);
                mreg[qf] = mn;
                float ts = 0.f;
                #pragma unroll
                for (int kvf = 0; kvf < 4; ++kvf)
                    #pragma unroll
                    for (int j = 0; j < 4; ++j) {
                        const float p = __expf(sT[kvf][qf][j] - mn);
                        sT[kvf][qf][j] = p;
                        ts += p;
                    }
                ts += __shfl_xor(ts, 16);
                ts += __shfl_xor(ts, 32);
                lreg[qf] = lreg[qf] * alphaq[qf] + ts;
            }
            #pragma unroll
            for (int qf = 0; qf < 2; ++qf) {
                float av[4];
                #pragma unroll
                for (int j = 0; j < 4; ++j) av[j] = __shfl(alphaq[qf], g * 4 + j);
                #pragma unroll
                for (int df = 0; df < 4; ++df)
                    #pragma unroll
                    for (int j = 0; j < 4; ++j) out[qf][df][j] *= av[j];
            }
            // ---- P^T -> P A-frags (shfl transpose) + PV (3-term split) ----
            #pragma unroll
            for (int kc = 0; kc < 2; ++kc) {
                bf16x8 phi[2], plo[2];
                #pragma unroll
                for (int qf = 0; qf < 2; ++qf) {
                    #pragma unroll
                    for (int m = 0; m < 8; ++m) {
                        const int src = ((g & 1) * 2 + (m >> 2)) * 16 + q15;
                        const float t0 = __shfl(sT[kc * 2 + 0][qf][m & 3], src);
                        const float t1 = __shfl(sT[kc * 2 + 1][qf][m & 3], src);
                        const float pvv = (g >= 2) ? t1 : t0;
                        const unsigned short hi = f2bf(pvv);
                        phi[qf][m] = (short)hi;
                        plo[qf][m] = (short)f2bf(pvv - bf2f(hi));
                    }
                }
                #pragma unroll
                for (int df = 0; df < 4; ++df) {
                    const int rowv = df * 16 + q15, swv = rowv & 7;
                    const bf16x8 vhi = *(const bf16x8*)&VsHi[rowv * 64 + ((kc * 4 + g) ^ swv) * 8];
                    const bf16x8 vlo = *(const bf16x8*)&VsLo[rowv * 64 + ((kc * 4 + g) ^ swv) * 8];
                    #pragma unroll
                    for (int qf = 0; qf < 2; ++qf) {
                        out[qf][df] = __builtin_amdgcn_mfma_f32_16x16x32_bf16(phi[qf], vhi, out[qf][df], 0, 0, 0);
                        out[qf][df] = __builtin_amdgcn_mfma_f32_16x16x32_bf16(phi[qf], vlo, out[qf][df], 0, 0, 0);
                        out[qf][df] = __builtin_amdgcn_mfma_f32_16x16x32_bf16(plo[qf], vhi, out[qf][df], 0, 0, 0);
                    }
                }
            }
        }
        __syncthreads();
    }

    // ---- epilogue: divide by l, split-bf16 store ----
    #pragma unroll
    for (int qf = 0; qf < 2; ++qf) {
        const float linv = 1.f / lreg[qf];
        float lv[4];
        #pragma unroll
        for (int j = 0; j < 4; ++j) lv[j] = __shfl(linv, g * 4 + j);
        #pragma unroll
        for (int df = 0; df < 4; ++df)
            #pragma unroll
            for (int j = 0; j < 4; ++j) {
                const float v = out[qf][df][j] * lv[j];
                const unsigned short hi = f2bf(v);
                const unsigned short lo = f2bf(v - bf2f(hi));
                const size_t m = (size_t)b * T + qw + qf * 16 + g * 4 + j;
                const int col = h * 64 + df * 16 + q15;
                ao2[m * 2048 + col] = hi;
                ao2[m * 2048 + 1024 + col] = lo;
            }
    }
}

// ---------------- weight transpose + split ----------------
__launch_bounds__(256)
__global__ void wsplit_t_k(const float* __restrict__ W, unsigned short* __restrict__ Wt2,
                           int K, int N, int ldo) {
    __shared__ float Tt[32][33];
    const int tx = threadIdx.x & 31, ty = threadIdx.x >> 5;
    const int k0 = blockIdx.y * 32, n0 = blockIdx.x * 32;
    #pragma unroll
    for (int i = 0; i < 4; ++i)
        Tt[i * 8 + ty][tx] = W[(size_t)(k0 + i * 8 + ty) * N + n0 + tx];
    __syncthreads();
    #pragma unroll
    for (int i = 0; i < 4; ++i) {
        const int r = i * 8 + ty;
        const float v = Tt[tx][r];
        const unsigned short hi = f2bf(v);
        const unsigned short lo = f2bf(v - bf2f(hi));
        Wt2[(size_t)(n0 + r) * ldo + k0 + tx] = hi;
        Wt2[(size_t)(n0 + r) * ldo + K + k0 + tx] = lo;
    }
}

// ---------------- activation split ----------------
__launch_bounds__(256)
__global__ void split2_k(const float* __restrict__ X, unsigned short* __restrict__ X2) {
    const int idx = (blockIdx.x * 256 + threadIdx.x) * 4;
    const int r = idx >> 10, c = idx & 1023;
    float4 v = *(const float4*)&X[idx];
    ushort4 h, lo;
    h.x = f2bf(v.x); lo.x = f2bf(v.x - bf2f(h.x));
    h.y = f2bf(v.y); lo.y = f2bf(v.y - bf2f(h.y));
    h.z = f2bf(v.z); lo.z = f2bf(v.z - bf2f(h.z));
    h.w = f2bf(v.w); lo.w = f2bf(v.w - bf2f(h.w));
    *(ushort4*)&X2[(size_t)r * 2048 + c] = h;
    *(ushort4*)&X2[(size_t)r * 2048 + 1024 + c] = lo;
}

__global__ void biascat_k(const float* a, const float* b, const float* c, float* o) {
    const int i = blockIdx.x * 256 + threadIdx.x;
    o[i] = (i < 1024) ? a[i] : ((i < 2048) ? b[i - 1024] : c[i - 2048]);
}

// ---------------- LayerNorm (in-place safe) ----------------
template<bool SPLIT>
__launch_bounds__(256)
__global__ void ln_k(const float* __restrict__ X, const float* __restrict__ g,
                     const float* __restrict__ b, float* __restrict__ Y,
                     unsigned short* __restrict__ Y2) {
    const int row = blockIdx.x;
    const int tid = threadIdx.x;
    const size_t off = (size_t)row * D_MODEL + tid * 4;
    float4 v = *(const float4*)&X[off];
    float s = v.x + v.y + v.z + v.w;
    float s2 = v.x * v.x + v.y * v.y + v.z * v.z + v.w * v.w;
    #pragma unroll
    for (int o = 1; o < 64; o <<= 1) { s += __shfl_xor(s, o); s2 += __shfl_xor(s2, o); }
    __shared__ float red[8];
    const int wid = tid >> 6, lane = tid & 63;
    if (lane == 0) { red[wid] = s; red[4 + wid] = s2; }
    __syncthreads();
    s = red[0] + red[1] + red[2] + red[3];
    s2 = red[4] + red[5] + red[6] + red[7];
    const float mu = s * (1.f / D_MODEL);
    const float var = s2 * (1.f / D_MODEL) - mu * mu;
    const float rst = rsqrtf(var + 1e-5f);
    float4 gv = *(const float4*)&g[tid * 4];
    float4 bv = *(const float4*)&b[tid * 4];
    float4 ov;
    ov.x = (v.x - mu) * rst * gv.x + bv.x;
    ov.y = (v.y - mu) * rst * gv.y + bv.y;
    ov.z = (v.z - mu) * rst * gv.z + bv.z;
    ov.w = (v.w - mu) * rst * gv.w + bv.w;
    *(float4*)&Y[off] = ov;
    if (SPLIT) {
        ushort4 h4, lo4;
        h4.x = f2bf(ov.x); lo4.x = f2bf(ov.x - bf2f(h4.x));
        h4.y = f2bf(ov.y); lo4.y = f2bf(ov.y - bf2f(h4.y));
        h4.z = f2bf(ov.z); lo4.z = f2bf(ov.z - bf2f(h4.z));
        h4.w = f2bf(ov.w); lo4.w = f2bf(ov.w - bf2f(h4.w));
        *(ushort4*)&Y2[(size_t)row * 2048 + tid * 4] = h4;
        *(ushort4*)&Y2[(size_t)row * 2048 + 1024 + tid * 4] = lo4;
    }
}

extern "C" void kernel_launch(void* const* d_in, const int* in_sizes, int n_in,
                              void* d_out, int out_size, void* d_ws, size_t ws_size,
                              hipStream_t stream) {
    (void)in_sizes; (void)n_in; (void)out_size; (void)ws_size;
    const float* x    = (const float*)d_in[0];
    const float* wq   = (const float*)d_in[1];
    const float* bq   = (const float*)d_in[2];
    const float* wk   = (const float*)d_in[3];
    const float* bk   = (const float*)d_in[4];
    const float* wv   = (const float*)d_in[5];
    const float* bv   = (const float*)d_in[6];
    const float* wo   = (const float*)d_in[7];
    const float* bo   = (const float*)d_in[8];
    const float* ln1g = (const float*)d_in[9];
    const float* ln1b = (const float*)d_in[10];
    const float* w1   = (const float*)d_in[11];
    const float* b1   = (const float*)d_in[12];
    const float* w2   = (const float*)d_in[13];
    const float* b2   = (const float*)d_in[14];
    const float* ln2g = (const float*)d_in[15];
    const float* ln2b = (const float*)d_in[16];
    float* out = (float*)d_out;

    const int B = 2, T = 2048, D = D_MODEL, F = D_FFC;
    const int M = B * T;

    // ws layout (byte offsets), peak 112 MB + 12 KB:
    //   [0,32)   qk2   (live step3->step5)        }  mid2 [0,64) at step9
    //   [32,48)  vT2   (live step3->step5)        }
    //   [48,64)  x2 (step2->3) -> ao2 (5->6)      }
    //   [64,80)  h12   (step8->9)
    //   [80,96)  wslotA: wqkv2t (1->3) -> w1t (4->9)
    //   [96,112) wslotB: wo2t (1->6) -> w2t (7->10)
    //   [112,+12K) bqkv
    char* ws = (char*)d_ws;
    const size_t MB = 1048576;
    unsigned short* qk2    = (unsigned short*)(ws + 0);
    unsigned short* mid2   = (unsigned short*)(ws + 0);
    unsigned short* vT2    = (unsigned short*)(ws + 32 * MB);
    unsigned short* x2     = (unsigned short*)(ws + 48 * MB);
    unsigned short* ao2    = (unsigned short*)(ws + 48 * MB);
    unsigned short* h12    = (unsigned short*)(ws + 64 * MB);
    unsigned short* wslotA = (unsigned short*)(ws + 80 * MB);
    unsigned short* wslotB = (unsigned short*)(ws + 96 * MB);
    float*          bqkv   = (float*)(ws + 112 * MB);

    dim3 blk(256);

    // 1. weight transpose+split: fused QKV [3072][2048] and Wo
    wsplit_t_k<<<dim3(32, 32), blk, 0, stream>>>(wq, wslotA + 0    * (size_t)2048, D, D, 2048);
    wsplit_t_k<<<dim3(32, 32), blk, 0, stream>>>(wk, wslotA + 1024 * (size_t)2048, D, D, 2048);
    wsplit_t_k<<<dim3(32, 32), blk, 0, stream>>>(wv, wslotA + 2048 * (size_t)2048, D, D, 2048);
    wsplit_t_k<<<dim3(32, 32), blk, 0, stream>>>(wo, wslotB, D, D, 2048);
    // 2. x -> split bf16; bias concat
    split2_k<<<4096, blk, 0, stream>>>(x, x2);
    biascat_k<<<12, blk, 0, stream>>>(bq, bk, bv, bqkv);

    // 3. fused QKV projection -> qk2 (Q scaled, split) + vT2 (V transposed, split)
    gemm_qkv<<<dim3(24, 32), blk, 0, stream>>>(x2, wslotA, bqkv, qk2, vT2, D, 3 * D);

    // 4. w1 transpose+split (reuses wqkv slot)
    wsplit_t_k<<<dim3(128, 32), blk, 0, stream>>>(w1, wslotA, D, F, 2048);

    // 5. MFMA flash attention -> ao2 split-bf16
    attn_mfma<<<dim3(32, 16), blk, 0, stream>>>(qk2, vT2, ao2);

    // 6. output projection + residual(x) -> d_out (pre-LN1, f32)
    gemm_sb<64, false, true, false><<<dim3(16, 32), blk, 0, stream>>>(
        ao2, wslotB, bo, x, out, D, D);

    // 7. w2 transpose+split (reuses wo slot)
    wsplit_t_k<<<dim3(32, 128), blk, 0, stream>>>(w2, wslotB, F, D, 8192);

    // 8. LN1 in-place on d_out + h12 split
    ln_k<true><<<M, blk, 0, stream>>>(out, ln1g, ln1b, out, h12);

    // 9. FFN1 + ReLU -> mid2 split-bf16
    gemm_sb<128, true, false, true><<<dim3(32, 32), blk, 0, stream>>>(
        h12, wslotA, b1, nullptr, mid2, D, F);

    // 10. FFN2 + residual(d_out) -> d_out in-place
    gemm_sb<64, false, true, false><<<dim3(16, 32), blk, 0, stream>>>(
        mid2, wslotB, b2, out, out, F, D);

    // 11. LN2 in-place
    ln_k<false><<<M, blk, 0, stream>>>(out, ln2g, ln2b, out, nullptr);
}

// Round 9
// 673.253 us; speedup vs baseline: 4.1177x; 1.1740x over previous
//
#include <hip/hip_runtime.h>
#include <math.h>

#define D_MODEL 1024
#define N_HEADSC 16
#define DKH 64
#define D_FFC 4096

typedef short bf16x8 __attribute__((ext_vector_type(8)));
typedef float f32x4 __attribute__((ext_vector_type(4)));

#define GLOAD_LDS16(g, l)                                                      \
    __builtin_amdgcn_global_load_lds(                                          \
        (const __attribute__((address_space(1))) void*)(g),                    \
        (__attribute__((address_space(3))) void*)(l), 16, 0, 0)

__device__ inline unsigned short f2bf(float f) {
    unsigned u = __float_as_uint(f);
    u += 0x7fff + ((u >> 16) & 1);
    return (unsigned short)(u >> 16);
}
__device__ inline float bf2f(unsigned short h) {
    return __uint_as_float(((unsigned)h) << 16);
}

// XCD-chunked bijective swizzle (requires nwg % 8 == 0; all grids here comply).
__device__ inline void xcd_swz(int& bx, int& by) {
    const int nwg = gridDim.x * gridDim.y;
    int lin = blockIdx.y * gridDim.x + blockIdx.x;
    const int q = nwg >> 3;
    lin = (lin & 7) * q + (lin >> 3);
    bx = lin % gridDim.x;
    by = lin / gridDim.x;
}

// ---------------- split-bf16 MFMA GEMM, single-K-pass fused 3-term ----------------
// A2: [M][2K] bf16 (hi|lo planes), Bt2: [N][2K] bf16 (W^T, hi|lo).
// C = Ahi*Whi + Ahi*Wlo + Alo*Whi ~= fp32 A@W, all terms in ONE pass over K.
template<int BN_, bool RELU, bool RES, bool SPLIT>
__launch_bounds__(256)
__global__ void gemm_sb(const unsigned short* __restrict__ A2,
                        const unsigned short* __restrict__ Bt2,
                        const float* __restrict__ bias,
                        const float* __restrict__ res,
                        void* __restrict__ Cout,
                        int K, int N) {
    constexpr int BM_ = 128;
    constexpr int WCOLS = BN_ / 2;
    constexpr int NT = WCOLS / 16;
    __shared__ unsigned short AsH[BM_ * 32], AsL[BM_ * 32];
    __shared__ unsigned short BsH[BN_ * 32], BsL[BN_ * 32];
    const int tid = threadIdx.x;
    const int l = tid & 63, w = tid >> 6;
    const int wrow = w >> 1, wcol = w & 1;
    int bx, by;
    xcd_swz(bx, by);
    const int brow = by * BM_;
    const int bcol = bx * BN_;
    const size_t ldk = 2 * (size_t)K;

    f32x4 acc[4][NT];
    #pragma unroll
    for (int mt = 0; mt < 4; ++mt)
        #pragma unroll
        for (int nt = 0; nt < NT; ++nt) acc[mt][nt] = (f32x4){0.f, 0.f, 0.f, 0.f};

    const int r0 = tid >> 2;           // staging row within 64
    const int c0 = (tid & 3) * 8;      // staging k-chunk
    const int lr = l & 15, kg = (l >> 4) * 8;

    #pragma unroll 1
    for (int kb = 0; kb < K; kb += 32) {
        const size_t arow0 = (size_t)(brow + r0) * ldk;
        const size_t arow1 = (size_t)(brow + 64 + r0) * ldk;
        GLOAD_LDS16(A2 + arow0 + kb + c0, &AsH[tid * 8]);
        GLOAD_LDS16(A2 + arow1 + kb + c0, &AsH[(256 + tid) * 8]);
        GLOAD_LDS16(A2 + arow0 + K + kb + c0, &AsL[tid * 8]);
        GLOAD_LDS16(A2 + arow1 + K + kb + c0, &AsL[(256 + tid) * 8]);
        const size_t brow0 = (size_t)(bcol + r0) * ldk;
        GLOAD_LDS16(Bt2 + brow0 + kb + c0, &BsH[tid * 8]);
        GLOAD_LDS16(Bt2 + brow0 + K + kb + c0, &BsL[tid * 8]);
        if constexpr (BN_ == 128) {
            const size_t brow1 = (size_t)(bcol + 64 + r0) * ldk;
            GLOAD_LDS16(Bt2 + brow1 + kb + c0, &BsH[(256 + tid) * 8]);
            GLOAD_LDS16(Bt2 + brow1 + K + kb + c0, &BsL[(256 + tid) * 8]);
        }
        __syncthreads();

        bf16x8 ah[4], al[4], bh[NT], bl[NT];
        #pragma unroll
        for (int mt = 0; mt < 4; ++mt) {
            const int ar = (wrow * 64 + mt * 16 + lr) * 32 + kg;
            ah[mt] = *(const bf16x8*)&AsH[ar];
            al[mt] = *(const bf16x8*)&AsL[ar];
        }
        #pragma unroll
        for (int nt = 0; nt < NT; ++nt) {
            const int br = (wcol * WCOLS + nt * 16 + lr) * 32 + kg;
            bh[nt] = *(const bf16x8*)&BsH[br];
            bl[nt] = *(const bf16x8*)&BsL[br];
        }
        #pragma unroll
        for (int mt = 0; mt < 4; ++mt)
            #pragma unroll
            for (int nt = 0; nt < NT; ++nt) {
                acc[mt][nt] = __builtin_amdgcn_mfma_f32_16x16x32_bf16(ah[mt], bh[nt], acc[mt][nt], 0, 0, 0);
                acc[mt][nt] = __builtin_amdgcn_mfma_f32_16x16x32_bf16(ah[mt], bl[nt], acc[mt][nt], 0, 0, 0);
                acc[mt][nt] = __builtin_amdgcn_mfma_f32_16x16x32_bf16(al[mt], bh[nt], acc[mt][nt], 0, 0, 0);
            }
        __syncthreads();
    }

    const int lg = l >> 4;
    #pragma unroll
    for (int mt = 0; mt < 4; ++mt) {
        #pragma unroll
        for (int nt = 0; nt < NT; ++nt) {
            #pragma unroll
            for (int j = 0; j < 4; ++j) {
                const int row = brow + wrow * 64 + mt * 16 + lg * 4 + j;
                const int col = bcol + wcol * WCOLS + nt * 16 + lr;
                float v = acc[mt][nt][j] + bias[col];
                if (RES) v += res[(size_t)row * N + col];
                if (RELU) v = fmaxf(v, 0.f);
                if (SPLIT) {
                    unsigned short hi = f2bf(v);
                    unsigned short lo = f2bf(v - bf2f(hi));
                    unsigned short* C = (unsigned short*)Cout;
                    C[(size_t)row * (2 * (size_t)N) + col] = hi;
                    C[(size_t)row * (2 * (size_t)N) + N + col] = lo;
                } else {
                    ((float*)Cout)[(size_t)row * N + col] = v;
                }
            }
        }
    }
}

// ---------------- QKV GEMM: fused single-pass core, attention-ready epilogue ----------------
__launch_bounds__(256)
__global__ void gemm_qkv(const unsigned short* __restrict__ A2,
                         const unsigned short* __restrict__ Bt2,
                         const float* __restrict__ bias,
                         unsigned short* __restrict__ qk2,
                         unsigned short* __restrict__ vT2,
                         int K, int N) {
    __shared__ unsigned short AsH[128 * 32], AsL[128 * 32];
    __shared__ unsigned short BsH[128 * 32], BsL[128 * 32];
    const int tid = threadIdx.x;
    const int l = tid & 63, w = tid >> 6;
    const int wrow = w >> 1, wcol = w & 1;
    int bx, by;
    xcd_swz(bx, by);
    const int brow = by * 128;
    const int bcol = bx * 128;
    const size_t ldk = 2 * (size_t)K;

    f32x4 acc[4][4];
    #pragma unroll
    for (int mt = 0; mt < 4; ++mt)
        #pragma unroll
        for (int nt = 0; nt < 4; ++nt) acc[mt][nt] = (f32x4){0.f, 0.f, 0.f, 0.f};

    const int r0 = tid >> 2;
    const int c0 = (tid & 3) * 8;
    const int lr = l & 15, kg = (l >> 4) * 8;

    #pragma unroll 1
    for (int kb = 0; kb < K; kb += 32) {
        const size_t arow0 = (size_t)(brow + r0) * ldk;
        const size_t arow1 = (size_t)(brow + 64 + r0) * ldk;
        GLOAD_LDS16(A2 + arow0 + kb + c0, &AsH[tid * 8]);
        GLOAD_LDS16(A2 + arow1 + kb + c0, &AsH[(256 + tid) * 8]);
        GLOAD_LDS16(A2 + arow0 + K + kb + c0, &AsL[tid * 8]);
        GLOAD_LDS16(A2 + arow1 + K + kb + c0, &AsL[(256 + tid) * 8]);
        const size_t brow0 = (size_t)(bcol + r0) * ldk;
        const size_t brow1 = (size_t)(bcol + 64 + r0) * ldk;
        GLOAD_LDS16(Bt2 + brow0 + kb + c0, &BsH[tid * 8]);
        GLOAD_LDS16(Bt2 + brow1 + kb + c0, &BsH[(256 + tid) * 8]);
        GLOAD_LDS16(Bt2 + brow0 + K + kb + c0, &BsL[tid * 8]);
        GLOAD_LDS16(Bt2 + brow1 + K + kb + c0, &BsL[(256 + tid) * 8]);
        __syncthreads();

        bf16x8 ah[4], al[4], bh[4], bl[4];
        #pragma unroll
        for (int mt = 0; mt < 4; ++mt) {
            const int ar = (wrow * 64 + mt * 16 + lr) * 32 + kg;
            ah[mt] = *(const bf16x8*)&AsH[ar];
            al[mt] = *(const bf16x8*)&AsL[ar];
        }
        #pragma unroll
        for (int nt = 0; nt < 4; ++nt) {
            const int br = (wcol * 64 + nt * 16 + lr) * 32 + kg;
            bh[nt] = *(const bf16x8*)&BsH[br];
            bl[nt] = *(const bf16x8*)&BsL[br];
        }
        #pragma unroll
        for (int mt = 0; mt < 4; ++mt)
            #pragma unroll
            for (int nt = 0; nt < 4; ++nt) {
                acc[mt][nt] = __builtin_amdgcn_mfma_f32_16x16x32_bf16(ah[mt], bh[nt], acc[mt][nt], 0, 0, 0);
                acc[mt][nt] = __builtin_amdgcn_mfma_f32_16x16x32_bf16(ah[mt], bl[nt], acc[mt][nt], 0, 0, 0);
                acc[mt][nt] = __builtin_amdgcn_mfma_f32_16x16x32_bf16(al[mt], bh[nt], acc[mt][nt], 0, 0, 0);
            }
        __syncthreads();
    }

    const int lg = l >> 4;
    #pragma unroll
    for (int mt = 0; mt < 4; ++mt) {
        #pragma unroll
        for (int nt = 0; nt < 4; ++nt) {
            #pragma unroll
            for (int j = 0; j < 4; ++j) {
                const int row = brow + wrow * 64 + mt * 16 + lg * 4 + j;
                const int col = bcol + wcol * 64 + nt * 16 + lr;
                float v = acc[mt][nt][j] + bias[col];
                if (col < 1024) v *= 0.125f;   // fold 1/sqrt(dk) into Q (exact)
                const unsigned short hi = f2bf(v);
                const unsigned short lo = f2bf(v - bf2f(hi));
                if (col < 2048) {
                    qk2[(size_t)row * 4096 + col] = hi;
                    qk2[(size_t)row * 4096 + 2048 + col] = lo;
                } else {
                    const int vc = col - 2048, hh = vc >> 6, dd = vc & 63;
                    const int bb = row >> 11, tt = row & 2047;
                    const size_t basev = ((size_t)((bb * 16 + hh) * 2) * 64 + dd) * 2048 + tt;
                    vT2[basev] = hi;
                    vT2[basev + (size_t)64 * 2048] = lo;
                }
            }
        }
    }
}

// ---------------- MFMA flash attention (causal), split-bf16 (round-5 verified) ----------------
__launch_bounds__(256)
__global__ void attn_mfma(const unsigned short* __restrict__ qk2,
                          const unsigned short* __restrict__ vT2,
                          unsigned short* __restrict__ ao2) {
    constexpr int T = 2048;
    __shared__ unsigned short KsHi[4096], KsLo[4096], VsHi[4096], VsLo[4096];

    const int tid = threadIdx.x;
    const int l = tid & 63, w = tid >> 6;
    const int g = l >> 4, q15 = l & 15;
    const int bh = blockIdx.x, b = bh >> 4, h = bh & 15;
    const int qbr = blockIdx.y;
    const int qb = (qbr < 8) ? qbr : 23 - qbr;
    const int qw = qb * 128 + w * 32;

    bf16x8 qhi[2][2], qlo[2][2];
    #pragma unroll
    for (int qf = 0; qf < 2; ++qf)
        #pragma unroll
        for (int kc = 0; kc < 2; ++kc) {
            const size_t m = (size_t)b * T + qw + qf * 16 + q15;
            qhi[qf][kc] = *(const bf16x8*)&qk2[m * 4096 + h * 64 + kc * 32 + g * 8];
            qlo[qf][kc] = *(const bf16x8*)&qk2[m * 4096 + 2048 + h * 64 + kc * 32 + g * 8];
        }

    f32x4 out[2][4];
    #pragma unroll
    for (int qf = 0; qf < 2; ++qf)
        #pragma unroll
        for (int df = 0; df < 4; ++df) out[qf][df] = (f32x4){0.f, 0.f, 0.f, 0.f};
    float mreg[2] = {-1e30f, -1e30f};
    float lreg[2] = {0.f, 0.f};

    const int ntiles = 2 * qb + 2;
    const size_t kvVbase0 = ((size_t)(bh * 2 + 0) * 64) * 2048;
    const size_t kvVbase1 = ((size_t)(bh * 2 + 1) * 64) * 2048;

    for (int kt = 0; kt < ntiles; ++kt) {
        const int kv0 = kt * 64;
        #pragma unroll
        for (int rr = 0; rr < 2; ++rr) {
            const int slot = rr * 256 + tid;
            const int row = slot >> 3, c = slot & 7;
            const int cs = (c ^ (row & 7)) * 8;
            const size_t krow = (size_t)(b * T + kv0 + row) * 4096;
            GLOAD_LDS16(qk2 + krow + 1024 + h * 64 + cs, &KsHi[slot * 8]);
            GLOAD_LDS16(qk2 + krow + 3072 + h * 64 + cs, &KsLo[slot * 8]);
            GLOAD_LDS16(vT2 + kvVbase0 + (size_t)row * 2048 + kv0 + cs, &VsHi[slot * 8]);
            GLOAD_LDS16(vT2 + kvVbase1 + (size_t)row * 2048 + kv0 + cs, &VsLo[slot * 8]);
        }
        __syncthreads();

        if (kv0 <= qw + 31) {
            f32x4 sT[4][2];
            #pragma unroll
            for (int kvf = 0; kvf < 4; ++kvf)
                #pragma unroll
                for (int qf = 0; qf < 2; ++qf) sT[kvf][qf] = (f32x4){0.f, 0.f, 0.f, 0.f};
            #pragma unroll
            for (int kvf = 0; kvf < 4; ++kvf) {
                const int rowk = kvf * 16 + q15, sw = rowk & 7;
                bf16x8 khi[2], klo[2];
                #pragma unroll
                for (int kc = 0; kc < 2; ++kc) {
                    khi[kc] = *(const bf16x8*)&KsHi[rowk * 64 + ((kc * 4 + g) ^ sw) * 8];
                    klo[kc] = *(const bf16x8*)&KsLo[rowk * 64 + ((kc * 4 + g) ^ sw) * 8];
                }
                #pragma unroll
                for (int qf = 0; qf < 2; ++qf)
                    #pragma unroll
                    for (int kc = 0; kc < 2; ++kc) {
                        sT[kvf][qf] = __builtin_amdgcn_mfma_f32_16x16x32_bf16(khi[kc], qhi[qf][kc], sT[kvf][qf], 0, 0, 0);
                        sT[kvf][qf] = __builtin_amdgcn_mfma_f32_16x16x32_bf16(khi[kc], qlo[qf][kc], sT[kvf][qf], 0, 0, 0);
                        sT[kvf][qf] = __builtin_amdgcn_mfma_f32_16x16x32_bf16(klo[kc], qhi[qf][kc], sT[kvf][qf], 0, 0, 0);
                    }
            }
            if (kv0 + 63 > qw) {
                #pragma unroll
                for (int kvf = 0; kvf < 4; ++kvf)
                    #pragma unroll
                    for (int qf = 0; qf < 2; ++qf)
                        #pragma unroll
                        for (int j = 0; j < 4; ++j) {
                            const int kvg = kv0 + kvf * 16 + g * 4 + j;
                            const int qg = qw + qf * 16 + q15;
                            if (kvg > qg) sT[kvf][qf][j] = -1e30f;
                        }
            }
            float alphaq[2];
            #pragma unroll
            for (int qf = 0; qf < 2; ++qf) {
                float tmax = -1e30f;
                #pragma unroll
                for (int kvf = 0; kvf < 4; ++kvf)
                    #pragma unroll
                    for (int j = 0; j < 4; ++j) tmax = fmaxf(tmax, sT[kvf][qf][j]);
                tmax = fmaxf(tmax, __shfl_xor(tmax, 16));
                tmax = fmaxf(tmax, __shfl_xor(tmax, 32));
                const float mn = fmaxf(mreg[qf], tmax);
                alphaq[qf] = __expf(mreg[qf] - mn);
                mreg[qf] = mn;
                float ts = 0.f;
                #pragma unroll
                for (int kvf = 0; kvf < 4; ++kvf)
                    #pragma unroll
                    for (int j = 0; j < 4; ++j) {
                        const float p = __expf(sT[kvf][qf][j] - mn);
                        sT[kvf][qf][j] = p;
                        ts += p;
                    }
                ts += __shfl_xor(ts, 16);
                ts += __shfl_xor(ts, 32);
                lreg[qf] = lreg[qf] * alphaq[qf] + ts;
            }
            #pragma unroll
            for (int qf = 0; qf < 2; ++qf) {
                float av[4];
                #pragma unroll
                for (int j = 0; j < 4; ++j) av[j] = __shfl(alphaq[qf], g * 4 + j);
                #pragma unroll
                for (int df = 0; df < 4; ++df)
                    #pragma unroll
                    for (int j = 0; j < 4; ++j) out[qf][df][j] *= av[j];
            }
            #pragma unroll
            for (int kc = 0; kc < 2; ++kc) {
                bf16x8 phi[2], plo[2];
                #pragma unroll
                for (int qf = 0; qf < 2; ++qf) {
                    #pragma unroll
                    for (int m = 0; m < 8; ++m) {
                        const int src = ((g & 1) * 2 + (m >> 2)) * 16 + q15;
                        const float t0 = __shfl(sT[kc * 2 + 0][qf][m & 3], src);
                        const float t1 = __shfl(sT[kc * 2 + 1][qf][m & 3], src);
                        const float pvv = (g >= 2) ? t1 : t0;
                        const unsigned short hi = f2bf(pvv);
                        phi[qf][m] = (short)hi;
                        plo[qf][m] = (short)f2bf(pvv - bf2f(hi));
                    }
                }
                #pragma unroll
                for (int df = 0; df < 4; ++df) {
                    const int rowv = df * 16 + q15, swv = rowv & 7;
                    const bf16x8 vhi = *(const bf16x8*)&VsHi[rowv * 64 + ((kc * 4 + g) ^ swv) * 8];
                    const bf16x8 vlo = *(const bf16x8*)&VsLo[rowv * 64 + ((kc * 4 + g) ^ swv) * 8];
                    #pragma unroll
                    for (int qf = 0; qf < 2; ++qf) {
                        out[qf][df] = __builtin_amdgcn_mfma_f32_16x16x32_bf16(phi[qf], vhi, out[qf][df], 0, 0, 0);
                        out[qf][df] = __builtin_amdgcn_mfma_f32_16x16x32_bf16(phi[qf], vlo, out[qf][df], 0, 0, 0);
                        out[qf][df] = __builtin_amdgcn_mfma_f32_16x16x32_bf16(plo[qf], vhi, out[qf][df], 0, 0, 0);
                    }
                }
            }
        }
        __syncthreads();
    }

    #pragma unroll
    for (int qf = 0; qf < 2; ++qf) {
        const float linv = 1.f / lreg[qf];
        float lv[4];
        #pragma unroll
        for (int j = 0; j < 4; ++j) lv[j] = __shfl(linv, g * 4 + j);
        #pragma unroll
        for (int df = 0; df < 4; ++df)
            #pragma unroll
            for (int j = 0; j < 4; ++j) {
                const float v = out[qf][df][j] * lv[j];
                const unsigned short hi = f2bf(v);
                const unsigned short lo = f2bf(v - bf2f(hi));
                const size_t m = (size_t)b * T + qw + qf * 16 + g * 4 + j;
                const int col = h * 64 + df * 16 + q15;
                ao2[m * 2048 + col] = hi;
                ao2[m * 2048 + 1024 + col] = lo;
            }
    }
}

// ---------------- weight transpose + split ----------------
__launch_bounds__(256)
__global__ void wsplit_t_k(const float* __restrict__ W, unsigned short* __restrict__ Wt2,
                           int K, int N, int ldo) {
    __shared__ float Tt[32][33];
    const int tx = threadIdx.x & 31, ty = threadIdx.x >> 5;
    const int k0 = blockIdx.y * 32, n0 = blockIdx.x * 32;
    #pragma unroll
    for (int i = 0; i < 4; ++i)
        Tt[i * 8 + ty][tx] = W[(size_t)(k0 + i * 8 + ty) * N + n0 + tx];
    __syncthreads();
    #pragma unroll
    for (int i = 0; i < 4; ++i) {
        const int r = i * 8 + ty;
        const float v = Tt[tx][r];
        const unsigned short hi = f2bf(v);
        const unsigned short lo = f2bf(v - bf2f(hi));
        Wt2[(size_t)(n0 + r) * ldo + k0 + tx] = hi;
        Wt2[(size_t)(n0 + r) * ldo + K + k0 + tx] = lo;
    }
}

// ---------------- activation split ----------------
__launch_bounds__(256)
__global__ void split2_k(const float* __restrict__ X, unsigned short* __restrict__ X2) {
    const int idx = (blockIdx.x * 256 + threadIdx.x) * 4;
    const int r = idx >> 10, c = idx & 1023;
    float4 v = *(const float4*)&X[idx];
    ushort4 h, lo;
    h.x = f2bf(v.x); lo.x = f2bf(v.x - bf2f(h.x));
    h.y = f2bf(v.y); lo.y = f2bf(v.y - bf2f(h.y));
    h.z = f2bf(v.z); lo.z = f2bf(v.z - bf2f(h.z));
    h.w = f2bf(v.w); lo.w = f2bf(v.w - bf2f(h.w));
    *(ushort4*)&X2[(size_t)r * 2048 + c] = h;
    *(ushort4*)&X2[(size_t)r * 2048 + 1024 + c] = lo;
}

__global__ void biascat_k(const float* a, const float* b, const float* c, float* o) {
    const int i = blockIdx.x * 256 + threadIdx.x;
    o[i] = (i < 1024) ? a[i] : ((i < 2048) ? b[i - 1024] : c[i - 2048]);
}

// ---------------- LayerNorm (in-place safe) ----------------
template<bool SPLIT>
__launch_bounds__(256)
__global__ void ln_k(const float* __restrict__ X, const float* __restrict__ g,
                     const float* __restrict__ b, float* __restrict__ Y,
                     unsigned short* __restrict__ Y2) {
    const int row = blockIdx.x;
    const int tid = threadIdx.x;
    const size_t off = (size_t)row * D_MODEL + tid * 4;
    float4 v = *(const float4*)&X[off];
    float s = v.x + v.y + v.z + v.w;
    float s2 = v.x * v.x + v.y * v.y + v.z * v.z + v.w * v.w;
    #pragma unroll
    for (int o = 1; o < 64; o <<= 1) { s += __shfl_xor(s, o); s2 += __shfl_xor(s2, o); }
    __shared__ float red[8];
    const int wid = tid >> 6, lane = tid & 63;
    if (lane == 0) { red[wid] = s; red[4 + wid] = s2; }
    __syncthreads();
    s = red[0] + red[1] + red[2] + red[3];
    s2 = red[4] + red[5] + red[6] + red[7];
    const float mu = s * (1.f / D_MODEL);
    const float var = s2 * (1.f / D_MODEL) - mu * mu;
    const float rst = rsqrtf(var + 1e-5f);
    float4 gv = *(const float4*)&g[tid * 4];
    float4 bv = *(const float4*)&b[tid * 4];
    float4 ov;
    ov.x = (v.x - mu) * rst * gv.x + bv.x;
    ov.y = (v.y - mu) * rst * gv.y + bv.y;
    ov.z = (v.z - mu) * rst * gv.z + bv.z;
    ov.w = (v.w - mu) * rst * gv.w + bv.w;
    *(float4*)&Y[off] = ov;
    if (SPLIT) {
        ushort4 h4, lo4;
        h4.x = f2bf(ov.x); lo4.x = f2bf(ov.x - bf2f(h4.x));
        h4.y = f2bf(ov.y); lo4.y = f2bf(ov.y - bf2f(h4.y));
        h4.z = f2bf(ov.z); lo4.z = f2bf(ov.z - bf2f(h4.z));
        h4.w = f2bf(ov.w); lo4.w = f2bf(ov.w - bf2f(h4.w));
        *(ushort4*)&Y2[(size_t)row * 2048 + tid * 4] = h4;
        *(ushort4*)&Y2[(size_t)row * 2048 + 1024 + tid * 4] = lo4;
    }
}

extern "C" void kernel_launch(void* const* d_in, const int* in_sizes, int n_in,
                              void* d_out, int out_size, void* d_ws, size_t ws_size,
                              hipStream_t stream) {
    (void)in_sizes; (void)n_in; (void)out_size; (void)ws_size;
    const float* x    = (const float*)d_in[0];
    const float* wq   = (const float*)d_in[1];
    const float* bq   = (const float*)d_in[2];
    const float* wk   = (const float*)d_in[3];
    const float* bk   = (const float*)d_in[4];
    const float* wv   = (const float*)d_in[5];
    const float* bv   = (const float*)d_in[6];
    const float* wo   = (const float*)d_in[7];
    const float* bo   = (const float*)d_in[8];
    const float* ln1g = (const float*)d_in[9];
    const float* ln1b = (const float*)d_in[10];
    const float* w1   = (const float*)d_in[11];
    const float* b1   = (const float*)d_in[12];
    const float* w2   = (const float*)d_in[13];
    const float* b2   = (const float*)d_in[14];
    const float* ln2g = (const float*)d_in[15];
    const float* ln2b = (const float*)d_in[16];
    float* out = (float*)d_out;

    const int B = 2, T = 2048, D = D_MODEL, F = D_FFC;
    const int M = B * T;

    // ws layout (byte offsets), peak 112 MB + 12 KB (same as round 5):
    char* ws = (char*)d_ws;
    const size_t MB = 1048576;
    unsigned short* qk2    = (unsigned short*)(ws + 0);
    unsigned short* mid2   = (unsigned short*)(ws + 0);
    unsigned short* vT2    = (unsigned short*)(ws + 32 * MB);
    unsigned short* x2     = (unsigned short*)(ws + 48 * MB);
    unsigned short* ao2    = (unsigned short*)(ws + 48 * MB);
    unsigned short* h12    = (unsigned short*)(ws + 64 * MB);
    unsigned short* wslotA = (unsigned short*)(ws + 80 * MB);
    unsigned short* wslotB = (unsigned short*)(ws + 96 * MB);
    float*          bqkv   = (float*)(ws + 112 * MB);

    dim3 blk(256);

    // 1. weight transpose+split: fused QKV [3072][2048] and Wo
    wsplit_t_k<<<dim3(32, 32), blk, 0, stream>>>(wq, wslotA + 0    * (size_t)2048, D, D, 2048);
    wsplit_t_k<<<dim3(32, 32), blk, 0, stream>>>(wk, wslotA + 1024 * (size_t)2048, D, D, 2048);
    wsplit_t_k<<<dim3(32, 32), blk, 0, stream>>>(wv, wslotA + 2048 * (size_t)2048, D, D, 2048);
    wsplit_t_k<<<dim3(32, 32), blk, 0, stream>>>(wo, wslotB, D, D, 2048);
    // 2. x -> split bf16; bias concat
    split2_k<<<4096, blk, 0, stream>>>(x, x2);
    biascat_k<<<12, blk, 0, stream>>>(bq, bk, bv, bqkv);

    // 3. fused QKV projection -> qk2 (Q scaled, split) + vT2 (V transposed, split)
    gemm_qkv<<<dim3(24, 32), blk, 0, stream>>>(x2, wslotA, bqkv, qk2, vT2, D, 3 * D);

    // 4. w1 transpose+split (reuses wqkv slot)
    wsplit_t_k<<<dim3(128, 32), blk, 0, stream>>>(w1, wslotA, D, F, 2048);

    // 5. MFMA flash attention -> ao2 split-bf16
    attn_mfma<<<dim3(32, 16), blk, 0, stream>>>(qk2, vT2, ao2);

    // 6. output projection + residual(x) -> d_out (pre-LN1, f32)
    gemm_sb<64, false, true, false><<<dim3(16, 32), blk, 0, stream>>>(
        ao2, wslotB, bo, x, out, D, D);

    // 7. w2 transpose+split (reuses wo slot)
    wsplit_t_k<<<dim3(32, 128), blk, 0, stream>>>(w2, wslotB, F, D, 8192);

    // 8. LN1 in-place on d_out + h12 split
    ln_k<true><<<M, blk, 0, stream>>>(out, ln1g, ln1b, out, h12);

    // 9. FFN1 + ReLU -> mid2 split-bf16
    gemm_sb<128, true, false, true><<<dim3(32, 32), blk, 0, stream>>>(
        h12, wslotA, b1, nullptr, mid2, D, F);

    // 10. FFN2 + residual(d_out) -> d_out in-place
    gemm_sb<64, false, true, false><<<dim3(16, 32), blk, 0, stream>>>(
        mid2, wslotB, b2, out, out, F, D);

    // 11. LN2 in-place
    ln_k<false><<<M, blk, 0, stream>>>(out, ln2g, ln2b, out, nullptr);
}